// Round 1
// baseline (1003.078 us; speedup 1.0000x reference)
//
#include <hip/hip_runtime.h>
#include <cstddef>

#define H_ 128
#define W_ 128
#define HW_ 16384
#define C_ 64
#define B_ 8
#define BHW_ 131072
#define EPS_ 1e-5f

// ---------------- prep: weight transposes + BN fold ----------------
// dwT[k*64+o] = dw[o*576+k]          (k = c*9+kk)
// w1f[c*64+o] = w1[o*64+c] * inv[o]  (inv = gamma*rsqrt(rvar+eps))
// w2T[c*64+o] = w2[o*64+c]
// b1f[o] = b1[o]*inv + beta[o] - rmean[o]*inv
__global__ __launch_bounds__(256) void prep_kernel(
    const float* __restrict__ dw, const float* __restrict__ w1,
    const float* __restrict__ b1, const float* __restrict__ gamma,
    const float* __restrict__ beta, const float* __restrict__ rmean,
    const float* __restrict__ rvar, const float* __restrict__ w2,
    float* __restrict__ dwT, float* __restrict__ w1f,
    float* __restrict__ w2T, float* __restrict__ b1f) {
  int i = blockIdx.x * 256 + threadIdx.x;
  if (i < 36864) {
    int o = i & 63, k = i >> 6;
    dwT[i] = dw[o * 576 + k];
  } else if (i < 36864 + 4096) {
    int j = i - 36864;
    int o = j & 63, c = j >> 6;
    float inv = gamma[o] * rsqrtf(rvar[o] + EPS_);
    w1f[c * 64 + o] = w1[o * 64 + c] * inv;
  } else if (i < 36864 + 8192) {
    int j = i - 36864 - 4096;
    int o = j & 63, c = j >> 6;
    w2T[c * 64 + o] = w2[o * 64 + c];
  } else if (i < 36864 + 8192 + 64) {
    int o = i - 36864 - 8192;
    float inv = gamma[o] * rsqrtf(rvar[o] + EPS_);
    b1f[o] = b1[o] * inv + beta[o] - rmean[o] * inv;
  }
}

// ---------------- avg pool 3x3, stride 1, pad 1, count_include_pad ----------------
__global__ __launch_bounds__(256) void avgpool_kernel(const float* __restrict__ xin,
                                                      float* __restrict__ p) {
  int i = blockIdx.x * 256 + threadIdx.x;  // over B*C*H*W
  int bc = i >> 14;
  int yx = i & 16383;
  int y = yx >> 7, x = yx & 127;
  const float* q = xin + (size_t)bc * HW_;
  float s = 0.f;
#pragma unroll
  for (int dy = -1; dy <= 1; ++dy) {
    int yy = y + dy;
    if ((unsigned)yy < 128u) {
      const float* row = q + yy * W_;
#pragma unroll
      for (int dx = -1; dx <= 1; ++dx) {
        int xx = x + dx;
        if ((unsigned)xx < 128u) s += row[xx];
      }
    }
  }
  p[i] = s * (1.f / 9.f);
}

// ---------------- offset conv: p(64ch) -> off(18ch), 3x3, pad 1 ----------------
// One thread per (oc, pixel); oc uniform per block (BHW_ % (256) == 0, 512 blocks/oc).
__global__ __launch_bounds__(256) void offconv_kernel(
    const float* __restrict__ p, const float* __restrict__ offw,
    const float* __restrict__ offb, float* __restrict__ off) {
  int tid = blockIdx.x * 256 + threadIdx.x;
  int oc = tid >> 17;          // / BHW_
  int pix = tid & (BHW_ - 1);
  int b = pix >> 14;
  int yx = pix & 16383;
  int y = yx >> 7, x = yx & 127;
  float acc = offb[oc];
  const float* wrow = offw + oc * 576;
  const float* pb = p + (size_t)b * C_ * HW_;
#pragma unroll
  for (int ky = 0; ky < 3; ++ky) {
    int yy = y + ky - 1;
    if ((unsigned)yy >= 128u) continue;
#pragma unroll
    for (int kx = 0; kx < 3; ++kx) {
      int xx = x + kx - 1;
      if ((unsigned)xx >= 128u) continue;
      const float* pp = pb + yy * W_ + xx;
      const float* wp = wrow + ky * 3 + kx;
#pragma unroll 8
      for (int c = 0; c < 64; ++c) acc += pp[c * HW_] * wp[c * 9];
    }
  }
  off[(size_t)(b * 18 + oc) * HW_ + yx] = acc;
}

// ---------------- deformable sample + K=576 GEMM ----------------
// Block: 256 threads, 16 consecutive pixels (same row: W=128 % 16 == 0).
__global__ __launch_bounds__(256) void deform_kernel(
    const float* __restrict__ p, const float* __restrict__ off,
    const float* __restrict__ dwT, const float* __restrict__ db,
    float* __restrict__ rbuf) {
  __shared__ float sLDS[576][16];   // 36864 B, sampled^T
  __shared__ float4 cw4[144];       // corner weights per (pix,kk)
  __shared__ int4 ci4[144];         // corner flat indices (clipped)
  int t = threadIdx.x;
  int pix0 = blockIdx.x * 16;
  int b = pix0 >> 14;
  int yx0 = pix0 & 16383;
  int y = yx0 >> 7, x0 = yx0 & 127;

  if (t < 144) {
    int pixl = t / 9, kk = t - pixl * 9;
    int xx = x0 + pixl;
    const float* ob = off + (size_t)(b * 18 + kk * 2) * HW_ + y * W_ + xx;
    float offy = ob[0];
    float offx = ob[HW_];
    float sy = (float)(y + (kk / 3) - 1) + offy;
    float sx = (float)(xx + (kk % 3) - 1) + offx;
    float fy = floorf(sy), fx = floorf(sx);
    float wy = sy - fy, wx = sx - fx;
    int iy = (int)fy, ix = (int)fx;
    float w[4];
    int id[4];
#pragma unroll
    for (int j = 0; j < 4; ++j) {
      int dy = j >> 1, dx = j & 1;
      int yc = iy + dy, xc = ix + dx;
      bool v = ((unsigned)yc < 128u) && ((unsigned)xc < 128u);
      int ycc = min(max(yc, 0), 127), xcc = min(max(xc, 0), 127);
      float wgt = (dy ? wy : 1.f - wy) * (dx ? wx : 1.f - wx);
      w[j] = v ? wgt : 0.f;
      id[j] = ycc * W_ + xcc;
    }
    cw4[t] = make_float4(w[0], w[1], w[2], w[3]);
    ci4[t] = make_int4(id[0], id[1], id[2], id[3]);
  }
  __syncthreads();

  const float* pb = p + (size_t)b * C_ * HW_;
#pragma unroll
  for (int it = 0; it < 36; ++it) {
    int v = it * 256 + t;  // 0..9215
    int c = v / 144;
    int pk = v - c * 144;
    int pixl = pk / 9, kk = pk - pixl * 9;
    const float* pc = pb + c * HW_;
    float4 w = cw4[pk];
    int4 id = ci4[pk];
    float val = w.x * pc[id.x] + w.y * pc[id.y] + w.z * pc[id.z] + w.w * pc[id.w];
    sLDS[c * 9 + kk][pixl] = val;
  }
  __syncthreads();

  int o = t & 63, pg = t >> 6;
  float dbo = db[o];
  float a0 = dbo, a1 = dbo, a2 = dbo, a3 = dbo;
  for (int k = 0; k < 576; ++k) {
    float wv = dwT[k * 64 + o];
    const float4 sv = *(const float4*)&sLDS[k][pg * 4];
    a0 += sv.x * wv;
    a1 += sv.y * wv;
    a2 += sv.z * wv;
    a3 += sv.w * wv;
  }
  // rbuf layout: [BHW][64] (pixel-major, channel contiguous) -> coalesced store
  float* rp = rbuf + (size_t)(pix0 + pg * 4) * 64 + o;
  rp[0] = a0;
  rp[64] = a1;
  rp[128] = a2;
  rp[192] = a3;
}

// ---------------- tail: conv1(1x1)+BN+ReLU + residual + conv2(1x1) ----------------
__global__ __launch_bounds__(256) void tail_kernel(
    const float* __restrict__ rbuf, const float* __restrict__ xin,
    const float* __restrict__ w1f, const float* __restrict__ b1f,
    const float* __restrict__ w2T, const float* __restrict__ b2,
    float* __restrict__ out) {
  __shared__ float rT[64][17];
  __shared__ float hT[64][17];
  int t = threadIdx.x;
  int pix0 = blockIdx.x * 16;
  int b = pix0 >> 14;
  int yx0 = pix0 & 16383;

  {  // load r tile [16 pix][64 ch] -> rT[c][pix]
    int pixl = t >> 4, c4 = (t & 15) * 4;
    const float4 rv = *(const float4*)(rbuf + (size_t)(pix0 + pixl) * 64 + c4);
    rT[c4][pixl] = rv.x;
    rT[c4 + 1][pixl] = rv.y;
    rT[c4 + 2][pixl] = rv.z;
    rT[c4 + 3][pixl] = rv.w;
  }
  __syncthreads();

  int o = t & 63, pg = t >> 6;
  float a0 = 0.f, a1 = 0.f, a2 = 0.f, a3 = 0.f;
#pragma unroll 8
  for (int k = 0; k < 64; ++k) {
    float wv = w1f[k * 64 + o];
    a0 += rT[k][pg * 4 + 0] * wv;
    a1 += rT[k][pg * 4 + 1] * wv;
    a2 += rT[k][pg * 4 + 2] * wv;
    a3 += rT[k][pg * 4 + 3] * wv;
  }
  float bb = b1f[o];
  const float* xp = xin + (size_t)(b * C_ + o) * HW_ + yx0 + pg * 4;
  const float4 xv = *(const float4*)xp;
  float h0 = fmaxf(a0 + bb, 0.f) + xv.x;
  float h1 = fmaxf(a1 + bb, 0.f) + xv.y;
  float h2 = fmaxf(a2 + bb, 0.f) + xv.z;
  float h3 = fmaxf(a3 + bb, 0.f) + xv.w;
  hT[o][pg * 4 + 0] = h0;
  hT[o][pg * 4 + 1] = h1;
  hT[o][pg * 4 + 2] = h2;
  hT[o][pg * 4 + 3] = h3;
  __syncthreads();

  float bo = b2[o];
  float c0 = bo, c1 = bo, c2 = bo, c3 = bo;
#pragma unroll 8
  for (int k = 0; k < 64; ++k) {
    float wv = w2T[k * 64 + o];
    c0 += hT[k][pg * 4 + 0] * wv;
    c1 += hT[k][pg * 4 + 1] * wv;
    c2 += hT[k][pg * 4 + 2] * wv;
    c3 += hT[k][pg * 4 + 3] * wv;
  }
  float* op = out + (size_t)(b * C_ + o) * HW_ + yx0 + pg * 4;
  *(float4*)op = make_float4(c0, c1, c2, c3);
}

extern "C" void kernel_launch(void* const* d_in, const int* in_sizes, int n_in,
                              void* d_out, int out_size, void* d_ws, size_t ws_size,
                              hipStream_t stream) {
  const float* x = (const float*)d_in[0];
  const float* offw = (const float*)d_in[1];
  const float* offb = (const float*)d_in[2];
  const float* dw = (const float*)d_in[3];
  const float* db = (const float*)d_in[4];
  const float* w1 = (const float*)d_in[5];
  const float* b1 = (const float*)d_in[6];
  const float* gamma = (const float*)d_in[7];
  const float* beta = (const float*)d_in[8];
  const float* rmean = (const float*)d_in[9];
  const float* rvar = (const float*)d_in[10];
  const float* w2 = (const float*)d_in[11];
  const float* b2 = (const float*)d_in[12];
  float* out = (float*)d_out;

  float* ws = (float*)d_ws;
  float* p = ws;                  // 8388608 f
  float* off = p + 8388608;       // 2359296 f
  float* rbuf = off + 2359296;    // 8388608 f
  float* dwT = rbuf + 8388608;    // 36864 f
  float* w1f = dwT + 36864;       // 4096 f
  float* w2T = w1f + 4096;        // 4096 f
  float* b1f = w2T + 4096;        // 64 f

  prep_kernel<<<177, 256, 0, stream>>>(dw, w1, b1, gamma, beta, rmean, rvar, w2,
                                       dwT, w1f, w2T, b1f);
  avgpool_kernel<<<32768, 256, 0, stream>>>(x, p);
  offconv_kernel<<<9216, 256, 0, stream>>>(p, offw, offb, off);
  deform_kernel<<<8192, 256, 0, stream>>>(p, off, dwT, db, rbuf);
  tail_kernel<<<8192, 256, 0, stream>>>(rbuf, x, w1f, b1f, w2T, b2, out);
}

// Round 2
// 583.861 us; speedup vs baseline: 1.7180x; 1.7180x over previous
//
#include <hip/hip_runtime.h>
#include <cstddef>

#define H_ 128
#define W_ 128
#define HW_ 16384
#define C_ 64
#define B_ 8
#define BHW_ 131072
#define EPS_ 1e-5f

// ---------------- prep: weight transposes + BN fold ----------------
__global__ __launch_bounds__(256) void prep_kernel(
    const float* __restrict__ dw, const float* __restrict__ w1,
    const float* __restrict__ b1, const float* __restrict__ gamma,
    const float* __restrict__ beta, const float* __restrict__ rmean,
    const float* __restrict__ rvar, const float* __restrict__ w2,
    float* __restrict__ dwT, float* __restrict__ w1f,
    float* __restrict__ w2T, float* __restrict__ b1f) {
  int i = blockIdx.x * 256 + threadIdx.x;
  if (i < 36864) {
    int o = i & 63, k = i >> 6;
    dwT[i] = dw[o * 576 + k];
  } else if (i < 36864 + 4096) {
    int j = i - 36864;
    int o = j & 63, c = j >> 6;
    float inv = gamma[o] * rsqrtf(rvar[o] + EPS_);
    w1f[c * 64 + o] = w1[o * 64 + c] * inv;
  } else if (i < 36864 + 8192) {
    int j = i - 36864 - 4096;
    int o = j & 63, c = j >> 6;
    w2T[c * 64 + o] = w2[o * 64 + c];
  } else if (i < 36864 + 8192 + 64) {
    int o = i - 36864 - 8192;
    float inv = gamma[o] * rsqrtf(rvar[o] + EPS_);
    b1f[o] = b1[o] * inv + beta[o] - rmean[o] * inv;
  }
}

// ---------------- avg pool 3x3, stride 1, pad 1, count_include_pad ----------------
__global__ __launch_bounds__(256) void avgpool_kernel(const float* __restrict__ xin,
                                                      float* __restrict__ p) {
  int i = blockIdx.x * 256 + threadIdx.x;  // over B*C*H*W
  int bc = i >> 14;
  int yx = i & 16383;
  int y = yx >> 7, x = yx & 127;
  const float* q = xin + (size_t)bc * HW_;
  float s = 0.f;
#pragma unroll
  for (int dy = -1; dy <= 1; ++dy) {
    int yy = y + dy;
    if ((unsigned)yy < 128u) {
      const float* row = q + yy * W_;
#pragma unroll
      for (int dx = -1; dx <= 1; ++dx) {
        int xx = x + dx;
        if ((unsigned)xx < 128u) s += row[xx];
      }
    }
  }
  p[i] = s * (1.f / 9.f);
}

// ---------------- offset conv: p(64ch) -> off(18ch), 3x3, pad 1 ----------------
// One block = 256 consecutive pixels; each thread computes ALL 18 ocs for its
// pixel so p is read from HBM exactly once. Weights staged in LDS as
// [kk*64+c][20] (18 ocs padded to 20 for b128 reads, wave-uniform broadcast).
__global__ __launch_bounds__(256) void offconv_kernel(
    const float* __restrict__ p, const float* __restrict__ offw,
    const float* __restrict__ offb, float* __restrict__ off) {
  __shared__ float wlds[576 * 20];  // 46080 B
  int t = threadIdx.x;

  // stage weights: wlds[(kk*64+c)*20 + oc] = offw[oc*576 + c*9 + kk]
#pragma unroll
  for (int it = 0; it < 45; ++it) {
    int i = it * 256 + t;           // 0..11519
    int kidx = i / 20;
    int oc = i - kidx * 20;
    int c = kidx & 63, kk = kidx >> 6;
    wlds[i] = (oc < 18) ? offw[oc * 576 + c * 9 + kk] : 0.f;
  }
  __syncthreads();

  int pix = blockIdx.x * 256 + t;
  int b = pix >> 14;
  int yx = pix & 16383;
  int y = yx >> 7, x = yx & 127;
  const float* pb = p + (size_t)b * C_ * HW_;

  int off9[9];
  float vm9[9];
#pragma unroll
  for (int kk = 0; kk < 9; ++kk) {
    int yy = y + (kk / 3) - 1;
    int xx = x + (kk % 3) - 1;
    bool v = ((unsigned)yy < 128u) && ((unsigned)xx < 128u);
    int yyc = min(max(yy, 0), 127), xxc = min(max(xx, 0), 127);
    off9[kk] = yyc * W_ + xxc;
    vm9[kk] = v ? 1.f : 0.f;
  }

  float acc[20];
#pragma unroll
  for (int j = 0; j < 20; ++j) acc[j] = 0.f;

#pragma unroll
  for (int kk = 0; kk < 9; ++kk) {
    const float* pk = pb + off9[kk];
    float vm = vm9[kk];
    const float* wk = wlds + kk * 64 * 20;
#pragma unroll 4
    for (int c = 0; c < 64; ++c) {
      float v = pk[c * HW_] * vm;
      const float4* w4 = (const float4*)(wk + c * 20);
#pragma unroll
      for (int j = 0; j < 5; ++j) {
        float4 w = w4[j];
        acc[j * 4 + 0] += v * w.x;
        acc[j * 4 + 1] += v * w.y;
        acc[j * 4 + 2] += v * w.z;
        acc[j * 4 + 3] += v * w.w;
      }
    }
  }

  float* op = off + (size_t)(b * 18) * HW_ + yx;
#pragma unroll
  for (int oc = 0; oc < 18; ++oc) op[(size_t)oc * HW_] = acc[oc] + offb[oc];
}

// ---------------- deformable sample + K=576 GEMM ----------------
__global__ __launch_bounds__(256) void deform_kernel(
    const float* __restrict__ p, const float* __restrict__ off,
    const float* __restrict__ dwT, const float* __restrict__ db,
    float* __restrict__ rbuf) {
  __shared__ float sLDS[576][16];   // 36864 B, sampled^T
  __shared__ float4 cw4[144];       // corner weights per (pix,kk)
  __shared__ int4 ci4[144];         // corner flat indices (clipped)
  int t = threadIdx.x;
  int pix0 = blockIdx.x * 16;
  int b = pix0 >> 14;
  int yx0 = pix0 & 16383;
  int y = yx0 >> 7, x0 = yx0 & 127;

  if (t < 144) {
    int pixl = t / 9, kk = t - pixl * 9;
    int xx = x0 + pixl;
    const float* ob = off + (size_t)(b * 18 + kk * 2) * HW_ + y * W_ + xx;
    float offy = ob[0];
    float offx = ob[HW_];
    float sy = (float)(y + (kk / 3) - 1) + offy;
    float sx = (float)(xx + (kk % 3) - 1) + offx;
    float fy = floorf(sy), fx = floorf(sx);
    float wy = sy - fy, wx = sx - fx;
    int iy = (int)fy, ix = (int)fx;
    float w[4];
    int id[4];
#pragma unroll
    for (int j = 0; j < 4; ++j) {
      int dy = j >> 1, dx = j & 1;
      int yc = iy + dy, xc = ix + dx;
      bool v = ((unsigned)yc < 128u) && ((unsigned)xc < 128u);
      int ycc = min(max(yc, 0), 127), xcc = min(max(xc, 0), 127);
      float wgt = (dy ? wy : 1.f - wy) * (dx ? wx : 1.f - wx);
      w[j] = v ? wgt : 0.f;
      id[j] = ycc * W_ + xcc;
    }
    cw4[t] = make_float4(w[0], w[1], w[2], w[3]);
    ci4[t] = make_int4(id[0], id[1], id[2], id[3]);
  }
  __syncthreads();

  const float* pb = p + (size_t)b * C_ * HW_;
#pragma unroll
  for (int it = 0; it < 36; ++it) {
    int v = it * 256 + t;  // 0..9215
    int c = v / 144;
    int pk = v - c * 144;
    int pixl = pk / 9, kk = pk - pixl * 9;
    const float* pc = pb + c * HW_;
    float4 w = cw4[pk];
    int4 id = ci4[pk];
    float val = w.x * pc[id.x] + w.y * pc[id.y] + w.z * pc[id.z] + w.w * pc[id.w];
    sLDS[c * 9 + kk][pixl] = val;
  }
  __syncthreads();

  int o = t & 63, pg = t >> 6;
  float dbo = db[o];
  float a0 = dbo, a1 = dbo, a2 = dbo, a3 = dbo;
  for (int k = 0; k < 576; ++k) {
    float wv = dwT[k * 64 + o];
    const float4 sv = *(const float4*)&sLDS[k][pg * 4];
    a0 += sv.x * wv;
    a1 += sv.y * wv;
    a2 += sv.z * wv;
    a3 += sv.w * wv;
  }
  float* rp = rbuf + (size_t)(pix0 + pg * 4) * 64 + o;
  rp[0] = a0;
  rp[64] = a1;
  rp[128] = a2;
  rp[192] = a3;
}

// ---------------- tail: conv1(1x1)+BN+ReLU + residual + conv2(1x1) ----------------
__global__ __launch_bounds__(256) void tail_kernel(
    const float* __restrict__ rbuf, const float* __restrict__ xin,
    const float* __restrict__ w1f, const float* __restrict__ b1f,
    const float* __restrict__ w2T, const float* __restrict__ b2,
    float* __restrict__ out) {
  __shared__ float rT[64][17];
  __shared__ float hT[64][17];
  int t = threadIdx.x;
  int pix0 = blockIdx.x * 16;
  int b = pix0 >> 14;
  int yx0 = pix0 & 16383;

  {
    int pixl = t >> 4, c4 = (t & 15) * 4;
    const float4 rv = *(const float4*)(rbuf + (size_t)(pix0 + pixl) * 64 + c4);
    rT[c4][pixl] = rv.x;
    rT[c4 + 1][pixl] = rv.y;
    rT[c4 + 2][pixl] = rv.z;
    rT[c4 + 3][pixl] = rv.w;
  }
  __syncthreads();

  int o = t & 63, pg = t >> 6;
  float a0 = 0.f, a1 = 0.f, a2 = 0.f, a3 = 0.f;
#pragma unroll 8
  for (int k = 0; k < 64; ++k) {
    float wv = w1f[k * 64 + o];
    a0 += rT[k][pg * 4 + 0] * wv;
    a1 += rT[k][pg * 4 + 1] * wv;
    a2 += rT[k][pg * 4 + 2] * wv;
    a3 += rT[k][pg * 4 + 3] * wv;
  }
  float bb = b1f[o];
  const float* xp = xin + (size_t)(b * C_ + o) * HW_ + yx0 + pg * 4;
  const float4 xv = *(const float4*)xp;
  float h0 = fmaxf(a0 + bb, 0.f) + xv.x;
  float h1 = fmaxf(a1 + bb, 0.f) + xv.y;
  float h2 = fmaxf(a2 + bb, 0.f) + xv.z;
  float h3 = fmaxf(a3 + bb, 0.f) + xv.w;
  hT[o][pg * 4 + 0] = h0;
  hT[o][pg * 4 + 1] = h1;
  hT[o][pg * 4 + 2] = h2;
  hT[o][pg * 4 + 3] = h3;
  __syncthreads();

  float bo = b2[o];
  float c0 = bo, c1 = bo, c2 = bo, c3 = bo;
#pragma unroll 8
  for (int k = 0; k < 64; ++k) {
    float wv = w2T[k * 64 + o];
    c0 += hT[k][pg * 4 + 0] * wv;
    c1 += hT[k][pg * 4 + 1] * wv;
    c2 += hT[k][pg * 4 + 2] * wv;
    c3 += hT[k][pg * 4 + 3] * wv;
  }
  float* op = out + (size_t)(b * C_ + o) * HW_ + yx0 + pg * 4;
  *(float4*)op = make_float4(c0, c1, c2, c3);
}

extern "C" void kernel_launch(void* const* d_in, const int* in_sizes, int n_in,
                              void* d_out, int out_size, void* d_ws, size_t ws_size,
                              hipStream_t stream) {
  const float* x = (const float*)d_in[0];
  const float* offw = (const float*)d_in[1];
  const float* offb = (const float*)d_in[2];
  const float* dw = (const float*)d_in[3];
  const float* db = (const float*)d_in[4];
  const float* w1 = (const float*)d_in[5];
  const float* b1 = (const float*)d_in[6];
  const float* gamma = (const float*)d_in[7];
  const float* beta = (const float*)d_in[8];
  const float* rmean = (const float*)d_in[9];
  const float* rvar = (const float*)d_in[10];
  const float* w2 = (const float*)d_in[11];
  const float* b2 = (const float*)d_in[12];
  float* out = (float*)d_out;

  float* ws = (float*)d_ws;
  float* p = ws;                  // 8388608 f
  float* off = p + 8388608;       // 2359296 f
  float* rbuf = off + 2359296;    // 8388608 f
  float* dwT = rbuf + 8388608;    // 36864 f
  float* w1f = dwT + 36864;       // 4096 f
  float* w2T = w1f + 4096;        // 4096 f
  float* b1f = w2T + 4096;        // 64 f

  prep_kernel<<<177, 256, 0, stream>>>(dw, w1, b1, gamma, beta, rmean, rvar, w2,
                                       dwT, w1f, w2T, b1f);
  avgpool_kernel<<<32768, 256, 0, stream>>>(x, p);
  offconv_kernel<<<512, 256, 0, stream>>>(p, offw, offb, off);
  deform_kernel<<<8192, 256, 0, stream>>>(p, off, dwT, db, rbuf);
  tail_kernel<<<8192, 256, 0, stream>>>(rbuf, x, w1f, b1f, w2T, b2, out);
}

// Round 7
// 455.102 us; speedup vs baseline: 2.2041x; 1.2829x over previous
//
#include <hip/hip_runtime.h>
#include <cstddef>

#define H_ 128
#define W_ 128
#define HW_ 16384
#define C_ 64
#define B_ 8
#define BHW_ 131072
#define EPS_ 1e-5f

typedef __attribute__((ext_vector_type(8))) short bf16x8;
typedef __attribute__((ext_vector_type(4))) float f32x4;

__device__ __forceinline__ unsigned short f2bf(float f) {
  unsigned u = __float_as_uint(f);
  unsigned r = (u + 0x7FFFu + ((u >> 16) & 1u)) >> 16;
  return (unsigned short)r;
}

// ---------------- prep: BN fold + plain bf16 cast of deform weights ----------
__global__ __launch_bounds__(256) void prep_kernel(
    const float* __restrict__ dw, const float* __restrict__ w1,
    const float* __restrict__ b1, const float* __restrict__ gamma,
    const float* __restrict__ beta, const float* __restrict__ rmean,
    const float* __restrict__ rvar, const float* __restrict__ w2,
    unsigned short* __restrict__ wbf, float* __restrict__ w1f,
    float* __restrict__ w2T, float* __restrict__ b1f) {
  int i = blockIdx.x * 256 + threadIdx.x;
  if (i < 36864) {
    wbf[i] = f2bf(dw[i]);
  } else if (i < 36864 + 4096) {
    int j = i - 36864;
    int o = j & 63, c = j >> 6;
    float inv = gamma[o] * rsqrtf(rvar[o] + EPS_);
    w1f[c * 64 + o] = w1[o * 64 + c] * inv;
  } else if (i < 36864 + 8192) {
    int j = i - 36864 - 4096;
    int o = j & 63, c = j >> 6;
    w2T[c * 64 + o] = w2[o * 64 + c];
  } else if (i < 36864 + 8192 + 64) {
    int o = i - 36864 - 8192;
    float inv = gamma[o] * rsqrtf(rvar[o] + EPS_);
    b1f[o] = b1[o] * inv + beta[o] - rmean[o] * inv;
  }
}

// ---------------- avg pool 3x3, stride 1, pad 1, count_include_pad ----------------
__global__ __launch_bounds__(256) void avgpool_kernel(const float* __restrict__ xin,
                                                      float* __restrict__ p) {
  int i = blockIdx.x * 256 + threadIdx.x;
  int bc = i >> 14;
  int yx = i & 16383;
  int y = yx >> 7, x = yx & 127;
  const float* q = xin + (size_t)bc * HW_;
  float s = 0.f;
#pragma unroll
  for (int dy = -1; dy <= 1; ++dy) {
    int yy = y + dy;
    if ((unsigned)yy < 128u) {
      const float* row = q + yy * W_;
#pragma unroll
      for (int dx = -1; dx <= 1; ++dx) {
        int xx = x + dx;
        if ((unsigned)xx < 128u) s += row[xx];
      }
    }
  }
  p[i] = s * (1.f / 9.f);
}

// ---------------- offset conv: p(64ch) -> off(18ch), 3x3, pad 1 ----------------
__global__ __launch_bounds__(256) void offconv_kernel(
    const float* __restrict__ p, const float* __restrict__ offw,
    const float* __restrict__ offb, float* __restrict__ off) {
  __shared__ float wlds[576 * 20];
  int t = threadIdx.x;
#pragma unroll
  for (int it = 0; it < 45; ++it) {
    int i = it * 256 + t;
    int kidx = i / 20;
    int oc = i - kidx * 20;
    int c = kidx & 63, kk = kidx >> 6;
    wlds[i] = (oc < 18) ? offw[oc * 576 + c * 9 + kk] : 0.f;
  }
  __syncthreads();

  int pix = blockIdx.x * 256 + t;
  int b = pix >> 14;
  int yx = pix & 16383;
  int y = yx >> 7, x = yx & 127;
  const float* pb = p + (size_t)b * C_ * HW_;

  int off9[9];
  float vm9[9];
#pragma unroll
  for (int kk = 0; kk < 9; ++kk) {
    int yy = y + (kk / 3) - 1;
    int xx = x + (kk % 3) - 1;
    bool v = ((unsigned)yy < 128u) && ((unsigned)xx < 128u);
    int yyc = min(max(yy, 0), 127), xxc = min(max(xx, 0), 127);
    off9[kk] = yyc * W_ + xxc;
    vm9[kk] = v ? 1.f : 0.f;
  }

  float acc[20];
#pragma unroll
  for (int j = 0; j < 20; ++j) acc[j] = 0.f;

#pragma unroll
  for (int kk = 0; kk < 9; ++kk) {
    const float* pk = pb + off9[kk];
    float vm = vm9[kk];
    const float* wk = wlds + kk * 64 * 20;
#pragma unroll 4
    for (int c = 0; c < 64; ++c) {
      float v = pk[c * HW_] * vm;
      const float4* w4 = (const float4*)(wk + c * 20);
#pragma unroll
      for (int j = 0; j < 5; ++j) {
        float4 w = w4[j];
        acc[j * 4 + 0] += v * w.x;
        acc[j * 4 + 1] += v * w.y;
        acc[j * 4 + 2] += v * w.z;
        acc[j * 4 + 3] += v * w.w;
      }
    }
  }

  float* op = off + (size_t)(b * 18) * HW_ + yx;
#pragma unroll
  for (int oc = 0; oc < 18; ++oc) op[(size_t)oc * HW_] = acc[oc] + offb[oc];
}

// ---------------- deformable sample (R2-proven structure) + proven MFMA ----
// Block: 256 thr (4 waves), 16 pixels. Sampling identical to R2 (t<144 param
// stage + 36-iter gather), destination transposed bf16 sAb[16][584].
// B staged per-288-chunk into sBb[64][296] with addressing formula identical
// to the A-fragment read (R6-verified pairing). Wave wv owns o-group wv.
__global__ __launch_bounds__(256, 2) void deform_kernel(
    const float* __restrict__ p, const float* __restrict__ off,
    const unsigned short* __restrict__ wbf, const float* __restrict__ db,
    float* __restrict__ rbuf) {
  __shared__ __align__(16) unsigned short sAb[16 * 584];  // 18688 B
  __shared__ __align__(16) unsigned short sBb[64 * 296];  // 37888 B
  __shared__ float4 cw4[144];
  __shared__ int4 ci4[144];
  int t = threadIdx.x;
  int lane = t & 63, wv = t >> 6;
  int pix0 = blockIdx.x * 16;
  int b = pix0 >> 14;
  int yx0 = pix0 & 16383;
  int y = yx0 >> 7, x0 = yx0 & 127;

  // ---- bilinear params (byte-identical to R2) ----
  if (t < 144) {
    int pixl = t / 9, kk = t - pixl * 9;
    int xx = x0 + pixl;
    const float* ob = off + (size_t)(b * 18 + kk * 2) * HW_ + y * W_ + xx;
    float offy = ob[0];
    float offx = ob[HW_];
    float sy = (float)(y + (kk / 3) - 1) + offy;
    float sx = (float)(xx + (kk % 3) - 1) + offx;
    float fy = floorf(sy), fx = floorf(sx);
    float wy = sy - fy, wx = sx - fx;
    int iy = (int)fy, ix = (int)fx;
    float w[4];
    int id[4];
#pragma unroll
    for (int j = 0; j < 4; ++j) {
      int dy = j >> 1, dx = j & 1;
      int yc = iy + dy, xc = ix + dx;
      bool v = ((unsigned)yc < 128u) && ((unsigned)xc < 128u);
      int ycc = min(max(yc, 0), 127), xcc = min(max(xc, 0), 127);
      float wgt = (dy ? wy : 1.f - wy) * (dx ? wx : 1.f - wx);
      w[j] = v ? wgt : 0.f;
      id[j] = ycc * W_ + xcc;
    }
    cw4[t] = make_float4(w[0], w[1], w[2], w[3]);
    ci4[t] = make_int4(id[0], id[1], id[2], id[3]);
  }
  // ---- stage B chunk 0 (k = 0..287) ----
#pragma unroll
  for (int it = 0; it < 9; ++it) {
    int i = it * 256 + t;  // 0..2303
    int o = i / 36, g = i - o * 36;
    *(uint4*)(sBb + o * 296 + g * 8) = *(const uint4*)(wbf + o * 576 + g * 8);
  }
  __syncthreads();

  // ---- sampling (R2-identical math; transposed bf16 destination) ----
  const float* pb = p + (size_t)b * C_ * HW_;
#pragma unroll
  for (int it = 0; it < 36; ++it) {
    int v = it * 256 + t;  // 0..9215
    int c = v / 144;
    int pk = v - c * 144;
    int pixl = pk / 9, kk = pk - pixl * 9;
    const float* pc = pb + c * HW_;
    float4 w = cw4[pk];
    int4 id = ci4[pk];
    float val = w.x * pc[id.x] + w.y * pc[id.y] + w.z * pc[id.z] + w.w * pc[id.w];
    sAb[pixl * 584 + c * 9 + kk] = f2bf(val);
  }
  __syncthreads();

  // ---- MFMA: wave wv computes o = wv*16 + (lane&15), pixels = rows ----
  f32x4 acc;
  {
    float d = db[wv * 16 + (lane & 15)];
    acc = (f32x4){d, d, d, d};
  }
  const unsigned short* arow = sAb + (lane & 15) * 584 + ((lane >> 4) << 3);
  const unsigned short* brow = sBb + (wv * 16 + (lane & 15)) * 296 + ((lane >> 4) << 3);

#pragma unroll
  for (int s = 0; s < 9; ++s) {
    bf16x8 a = *(const bf16x8*)(arow + s * 32);
    bf16x8 bw = *(const bf16x8*)(brow + s * 32);
    acc = __builtin_amdgcn_mfma_f32_16x16x32_bf16(a, bw, acc, 0, 0, 0);
  }
  __syncthreads();  // chunk-0 B reads complete before overwrite

  // ---- stage B chunk 1 (k = 288..575) ----
#pragma unroll
  for (int it = 0; it < 9; ++it) {
    int i = it * 256 + t;
    int o = i / 36, g = i - o * 36;
    *(uint4*)(sBb + o * 296 + g * 8) = *(const uint4*)(wbf + o * 576 + 288 + g * 8);
  }
  __syncthreads();

#pragma unroll
  for (int s = 0; s < 9; ++s) {
    bf16x8 a = *(const bf16x8*)(arow + 288 + s * 32);
    bf16x8 bw = *(const bf16x8*)(brow + s * 32);
    acc = __builtin_amdgcn_mfma_f32_16x16x32_bf16(a, bw, acc, 0, 0, 0);
  }

  // ---- D store (R6-verified layout): row = (lane>>4)*4 + j, col = lane&15 ----
  int prow = pix0 + ((lane >> 4) << 2);
  int ocol = wv * 16 + (lane & 15);
#pragma unroll
  for (int j = 0; j < 4; ++j) {
    rbuf[(size_t)(prow + j) * 64 + ocol] = acc[j];
  }
}

// ---------------- tail: conv1(1x1)+BN+ReLU + residual + conv2(1x1) ----------------
__global__ __launch_bounds__(256) void tail_kernel(
    const float* __restrict__ rbuf, const float* __restrict__ xin,
    const float* __restrict__ w1f, const float* __restrict__ b1f,
    const float* __restrict__ w2T, const float* __restrict__ b2,
    float* __restrict__ out) {
  __shared__ float rT[64][17];
  __shared__ float hT[64][17];
  int t = threadIdx.x;
  int pix0 = blockIdx.x * 16;
  int b = pix0 >> 14;
  int yx0 = pix0 & 16383;

  {
    int pixl = t >> 4, c4 = (t & 15) * 4;
    const float4 rv = *(const float4*)(rbuf + (size_t)(pix0 + pixl) * 64 + c4);
    rT[c4][pixl] = rv.x;
    rT[c4 + 1][pixl] = rv.y;
    rT[c4 + 2][pixl] = rv.z;
    rT[c4 + 3][pixl] = rv.w;
  }
  __syncthreads();

  int o = t & 63, pg = t >> 6;
  float a0 = 0.f, a1 = 0.f, a2 = 0.f, a3 = 0.f;
#pragma unroll 8
  for (int k = 0; k < 64; ++k) {
    float wv = w1f[k * 64 + o];
    a0 += rT[k][pg * 4 + 0] * wv;
    a1 += rT[k][pg * 4 + 1] * wv;
    a2 += rT[k][pg * 4 + 2] * wv;
    a3 += rT[k][pg * 4 + 3] * wv;
  }
  float bb = b1f[o];
  const float* xp = xin + (size_t)(b * C_ + o) * HW_ + yx0 + pg * 4;
  const float4 xv = *(const float4*)xp;
  float h0 = fmaxf(a0 + bb, 0.f) + xv.x;
  float h1 = fmaxf(a1 + bb, 0.f) + xv.y;
  float h2 = fmaxf(a2 + bb, 0.f) + xv.z;
  float h3 = fmaxf(a3 + bb, 0.f) + xv.w;
  hT[o][pg * 4 + 0] = h0;
  hT[o][pg * 4 + 1] = h1;
  hT[o][pg * 4 + 2] = h2;
  hT[o][pg * 4 + 3] = h3;
  __syncthreads();

  float bo = b2[o];
  float c0 = bo, c1 = bo, c2 = bo, c3 = bo;
#pragma unroll 8
  for (int k = 0; k < 64; ++k) {
    float wv = w2T[k * 64 + o];
    c0 += hT[k][pg * 4 + 0] * wv;
    c1 += hT[k][pg * 4 + 1] * wv;
    c2 += hT[k][pg * 4 + 2] * wv;
    c3 += hT[k][pg * 4 + 3] * wv;
  }
  float* op = out + (size_t)(b * C_ + o) * HW_ + yx0 + pg * 4;
  *(float4*)op = make_float4(c0, c1, c2, c3);
}

extern "C" void kernel_launch(void* const* d_in, const int* in_sizes, int n_in,
                              void* d_out, int out_size, void* d_ws, size_t ws_size,
                              hipStream_t stream) {
  const float* x = (const float*)d_in[0];
  const float* offw = (const float*)d_in[1];
  const float* offb = (const float*)d_in[2];
  const float* dw = (const float*)d_in[3];
  const float* db = (const float*)d_in[4];
  const float* w1 = (const float*)d_in[5];
  const float* b1 = (const float*)d_in[6];
  const float* gamma = (const float*)d_in[7];
  const float* beta = (const float*)d_in[8];
  const float* rmean = (const float*)d_in[9];
  const float* rvar = (const float*)d_in[10];
  const float* w2 = (const float*)d_in[11];
  const float* b2 = (const float*)d_in[12];
  float* out = (float*)d_out;

  float* ws = (float*)d_ws;
  float* p = ws;                        // 8388608 f
  float* off = p + 8388608;             // 2359296 f
  float* rbuf = off + 2359296;          // 8388608 f
  unsigned short* wbf = (unsigned short*)(rbuf + 8388608);  // 36864 bf16
  float* w1f = rbuf + 8388608 + 36864;  // 4096 f
  float* w2T = w1f + 4096;              // 4096 f
  float* b1f = w2T + 4096;              // 64 f

  prep_kernel<<<177, 256, 0, stream>>>(dw, w1, b1, gamma, beta, rmean, rvar, w2,
                                       wbf, w1f, w2T, b1f);
  avgpool_kernel<<<32768, 256, 0, stream>>>(x, p);
  offconv_kernel<<<512, 256, 0, stream>>>(p, offw, offb, off);
  deform_kernel<<<8192, 256, 0, stream>>>(p, off, wbf, db, rbuf);
  tail_kernel<<<8192, 256, 0, stream>>>(rbuf, x, w1f, b1f, w2T, b2, out);
}

// Round 8
// 277.690 us; speedup vs baseline: 3.6122x; 1.6389x over previous
//
#include <hip/hip_runtime.h>
#include <cstddef>

#define H_ 128
#define W_ 128
#define HW_ 16384
#define C_ 64
#define B_ 8
#define BHW_ 131072
#define EPS_ 1e-5f

typedef __attribute__((ext_vector_type(8))) short bf16x8;
typedef __attribute__((ext_vector_type(4))) float f32x4;

__device__ __forceinline__ unsigned short f2bf(float f) {
  unsigned u = __float_as_uint(f);
  unsigned r = (u + 0x7FFFu + ((u >> 16) & 1u)) >> 16;
  return (unsigned short)r;
}

// ---------------- prep: BN fold + MFMA-fragment-packed bf16 deform weights ----
// wf[((sg*4+og)*64 + l)*8 + j] = bf16(dw[o*576 + k]),
//   o = og*16 + (l&15), k = sg*32 + ((l>>4)<<3) + j.
// Value-identical to R7's proven LDS addressing (sBb[o][(l>>4)*8 + s*32 + j]).
__global__ __launch_bounds__(256) void prep_kernel(
    const float* __restrict__ dw, const float* __restrict__ w1,
    const float* __restrict__ b1, const float* __restrict__ gamma,
    const float* __restrict__ beta, const float* __restrict__ rmean,
    const float* __restrict__ rvar, const float* __restrict__ w2,
    unsigned short* __restrict__ wf, float* __restrict__ w1f,
    float* __restrict__ w2T, float* __restrict__ b1f) {
  int i = blockIdx.x * 256 + threadIdx.x;
  if (i < 36864) {
    int j = i & 7, l = (i >> 3) & 63, og = (i >> 9) & 3, sg = i >> 11;
    int o = og * 16 + (l & 15);
    int k = sg * 32 + ((l >> 4) << 3) + j;
    wf[i] = f2bf(dw[o * 576 + k]);
  } else if (i < 36864 + 4096) {
    int j = i - 36864;
    int o = j & 63, c = j >> 6;
    float inv = gamma[o] * rsqrtf(rvar[o] + EPS_);
    w1f[c * 64 + o] = w1[o * 64 + c] * inv;
  } else if (i < 36864 + 8192) {
    int j = i - 36864 - 4096;
    int o = j & 63, c = j >> 6;
    w2T[c * 64 + o] = w2[o * 64 + c];
  } else if (i < 36864 + 8192 + 64) {
    int o = i - 36864 - 8192;
    float inv = gamma[o] * rsqrtf(rvar[o] + EPS_);
    b1f[o] = b1[o] * inv + beta[o] - rmean[o] * inv;
  }
}

// ---------------- avg pool 3x3, stride 1, pad 1, count_include_pad ----------------
__global__ __launch_bounds__(256) void avgpool_kernel(const float* __restrict__ xin,
                                                      float* __restrict__ p) {
  int i = blockIdx.x * 256 + threadIdx.x;
  int bc = i >> 14;
  int yx = i & 16383;
  int y = yx >> 7, x = yx & 127;
  const float* q = xin + (size_t)bc * HW_;
  float s = 0.f;
#pragma unroll
  for (int dy = -1; dy <= 1; ++dy) {
    int yy = y + dy;
    if ((unsigned)yy < 128u) {
      const float* row = q + yy * W_;
#pragma unroll
      for (int dx = -1; dx <= 1; ++dx) {
        int xx = x + dx;
        if ((unsigned)xx < 128u) s += row[xx];
      }
    }
  }
  p[i] = s * (1.f / 9.f);
}

// ---------------- offset conv: p(64ch) -> off(18ch), 3x3, pad 1 ----------------
__global__ __launch_bounds__(256) void offconv_kernel(
    const float* __restrict__ p, const float* __restrict__ offw,
    const float* __restrict__ offb, float* __restrict__ off) {
  __shared__ float wlds[576 * 20];
  int t = threadIdx.x;
#pragma unroll
  for (int it = 0; it < 45; ++it) {
    int i = it * 256 + t;
    int kidx = i / 20;
    int oc = i - kidx * 20;
    int c = kidx & 63, kk = kidx >> 6;
    wlds[i] = (oc < 18) ? offw[oc * 576 + c * 9 + kk] : 0.f;
  }
  __syncthreads();

  int pix = blockIdx.x * 256 + t;
  int b = pix >> 14;
  int yx = pix & 16383;
  int y = yx >> 7, x = yx & 127;
  const float* pb = p + (size_t)b * C_ * HW_;

  int off9[9];
  float vm9[9];
#pragma unroll
  for (int kk = 0; kk < 9; ++kk) {
    int yy = y + (kk / 3) - 1;
    int xx = x + (kk % 3) - 1;
    bool v = ((unsigned)yy < 128u) && ((unsigned)xx < 128u);
    int yyc = min(max(yy, 0), 127), xxc = min(max(xx, 0), 127);
    off9[kk] = yyc * W_ + xxc;
    vm9[kk] = v ? 1.f : 0.f;
  }

  float acc[20];
#pragma unroll
  for (int j = 0; j < 20; ++j) acc[j] = 0.f;

#pragma unroll
  for (int kk = 0; kk < 9; ++kk) {
    const float* pk = pb + off9[kk];
    float vm = vm9[kk];
    const float* wk = wlds + kk * 64 * 20;
#pragma unroll 4
    for (int c = 0; c < 64; ++c) {
      float v = pk[c * HW_] * vm;
      const float4* w4 = (const float4*)(wk + c * 20);
#pragma unroll
      for (int j = 0; j < 5; ++j) {
        float4 w = w4[j];
        acc[j * 4 + 0] += v * w.x;
        acc[j * 4 + 1] += v * w.y;
        acc[j * 4 + 2] += v * w.z;
        acc[j * 4 + 3] += v * w.w;
      }
    }
  }

  float* op = off + (size_t)(b * 18) * HW_ + yx;
#pragma unroll
  for (int oc = 0; oc < 18; ++oc) op[(size_t)oc * HW_] = acc[oc] + offb[oc];
}

// ---------------- deformable sample (LDS-tiled fast path) + proven MFMA ----
// Block: 256 thr (4 waves), 16 pixels. p-tile [64][5][20] staged in LDS;
// fast path (offsets within tile — always true for this data) samples from
// LDS; slow path = R7-proven global gather. MFMA identical to R7 with B from
// prep-packed global fragments.
__global__ __launch_bounds__(256, 3) void deform_kernel(
    const float* __restrict__ p, const float* __restrict__ off,
    const unsigned short* __restrict__ wf, const float* __restrict__ db,
    float* __restrict__ rbuf) {
  __shared__ __align__(16) float tileT[64 * 100];        // 25600 B
  __shared__ __align__(16) unsigned short sAb[16 * 584]; // 18688 B
  __shared__ float4 cw4[144];
  __shared__ int4 ci4[144];
  __shared__ uchar4 rel4[144];
  __shared__ int wOK[4];
  int t = threadIdx.x;
  int lane = t & 63, wv = t >> 6;
  int pix0 = blockIdx.x * 16;
  int b = pix0 >> 14;
  int yx0 = pix0 & 16383;
  int y = yx0 >> 7, x0 = yx0 & 127;
  int ty = min(max(y - 2, 0), 123);
  int tx = min(max(x0 - 2, 0), 108);
  const float* pb = p + (size_t)b * C_ * HW_;

  // ---- bilinear params (R7-identical math) + in-tile check ----
  bool ok = true;
  if (t < 144) {
    int pixl = t / 9, kk = t - pixl * 9;
    int xx = x0 + pixl;
    const float* ob = off + (size_t)(b * 18 + kk * 2) * HW_ + y * W_ + xx;
    float offy = ob[0];
    float offx = ob[HW_];
    float sy = (float)(y + (kk / 3) - 1) + offy;
    float sx = (float)(xx + (kk % 3) - 1) + offx;
    float fy = floorf(sy), fx = floorf(sx);
    float wy = sy - fy, wx = sx - fx;
    int iy = (int)fy, ix = (int)fx;
    float w[4];
    int id[4];
    unsigned rel[4];
#pragma unroll
    for (int j = 0; j < 4; ++j) {
      int dy = j >> 1, dx = j & 1;
      int yc = iy + dy, xc = ix + dx;
      bool v = ((unsigned)yc < 128u) && ((unsigned)xc < 128u);
      int ycc = min(max(yc, 0), 127), xcc = min(max(xc, 0), 127);
      float wgt = (dy ? wy : 1.f - wy) * (dx ? wx : 1.f - wx);
      w[j] = v ? wgt : 0.f;
      id[j] = ycc * W_ + xcc;
      bool in_tile = (ycc >= ty) && (ycc <= ty + 4) && (xcc >= tx) && (xcc <= tx + 19);
      ok = ok && ((w[j] == 0.f) || in_tile);
      int ry = min(max(ycc - ty, 0), 4);
      int rx = min(max(xcc - tx, 0), 19);
      rel[j] = (unsigned)(ry * 20 + rx);
    }
    cw4[t] = make_float4(w[0], w[1], w[2], w[3]);
    ci4[t] = make_int4(id[0], id[1], id[2], id[3]);
    rel4[t] = make_uchar4((unsigned char)rel[0], (unsigned char)rel[1],
                          (unsigned char)rel[2], (unsigned char)rel[3]);
  }
  {
    unsigned long long m = __ballot(ok);
    if (lane == 0) wOK[wv] = (m == ~0ull) ? 1 : 0;
  }

  // ---- stage p-tile [64ch][5r][20c] (always in-bounds by ty/tx clamping) ----
#pragma unroll
  for (int i = 0; i < 25; ++i) {
    int idx = i * 256 + t;  // 0..6399
    int c = idx / 100;
    int rc = idx - c * 100;
    int r = rc / 20, cx = rc - r * 20;
    tileT[idx] = pb[(size_t)c * HW_ + (ty + r) * W_ + tx + cx];
  }
  __syncthreads();

  bool fast = wOK[0] && wOK[1] && wOK[2] && wOK[3];

  // ---- sampling into sAb[pix][584] ----
  if (fast) {
#pragma unroll
    for (int it = 0; it < 36; ++it) {
      int v = it * 256 + t;  // 0..9215
      int c = v / 144;
      int pk = v - c * 144;
      int pixl = pk / 9, kk = pk - pixl * 9;
      const float* tc = tileT + c * 100;
      float4 w = cw4[pk];
      uchar4 rl = rel4[pk];
      float val = w.x * tc[rl.x] + w.y * tc[rl.y] + w.z * tc[rl.z] + w.w * tc[rl.w];
      sAb[pixl * 584 + c * 9 + kk] = f2bf(val);
    }
  } else {
#pragma unroll
    for (int it = 0; it < 36; ++it) {
      int v = it * 256 + t;
      int c = v / 144;
      int pk = v - c * 144;
      int pixl = pk / 9, kk = pk - pixl * 9;
      const float* pc = pb + (size_t)c * HW_;
      float4 w = cw4[pk];
      int4 id = ci4[pk];
      float val = w.x * pc[id.x] + w.y * pc[id.y] + w.z * pc[id.z] + w.w * pc[id.w];
      sAb[pixl * 584 + c * 9 + kk] = f2bf(val);
    }
  }
  __syncthreads();

  // ---- MFMA: wave wv owns o = wv*16 + (lane&15); B from global wf ----
  f32x4 acc;
  {
    float d = db[wv * 16 + (lane & 15)];
    acc = (f32x4){d, d, d, d};
  }
  const unsigned short* arow = sAb + (lane & 15) * 584 + ((lane >> 4) << 3);
  const bf16x8* wf8 = (const bf16x8*)wf;

#pragma unroll
  for (int ch = 0; ch < 2; ++ch) {
#pragma unroll
    for (int s = 0; s < 9; ++s) {
      bf16x8 a = *(const bf16x8*)(arow + ch * 288 + s * 32);
      bf16x8 bw = wf8[((ch * 9 + s) * 4 + wv) * 64 + lane];
      acc = __builtin_amdgcn_mfma_f32_16x16x32_bf16(a, bw, acc, 0, 0, 0);
    }
  }

  // ---- D store (verified): row = (lane>>4)*4 + j, col = lane&15 ----
  int prow = pix0 + ((lane >> 4) << 2);
  int ocol = wv * 16 + (lane & 15);
#pragma unroll
  for (int j = 0; j < 4; ++j) {
    rbuf[(size_t)(prow + j) * 64 + ocol] = acc[j];
  }
}

// ---------------- tail: conv1(1x1)+BN+ReLU + residual + conv2(1x1) ----------------
__global__ __launch_bounds__(256) void tail_kernel(
    const float* __restrict__ rbuf, const float* __restrict__ xin,
    const float* __restrict__ w1f, const float* __restrict__ b1f,
    const float* __restrict__ w2T, const float* __restrict__ b2,
    float* __restrict__ out) {
  __shared__ float rT[64][17];
  __shared__ float hT[64][17];
  int t = threadIdx.x;
  int pix0 = blockIdx.x * 16;
  int b = pix0 >> 14;
  int yx0 = pix0 & 16383;

  {
    int pixl = t >> 4, c4 = (t & 15) * 4;
    const float4 rv = *(const float4*)(rbuf + (size_t)(pix0 + pixl) * 64 + c4);
    rT[c4][pixl] = rv.x;
    rT[c4 + 1][pixl] = rv.y;
    rT[c4 + 2][pixl] = rv.z;
    rT[c4 + 3][pixl] = rv.w;
  }
  __syncthreads();

  int o = t & 63, pg = t >> 6;
  float a0 = 0.f, a1 = 0.f, a2 = 0.f, a3 = 0.f;
#pragma unroll 8
  for (int k = 0; k < 64; ++k) {
    float wv = w1f[k * 64 + o];
    a0 += rT[k][pg * 4 + 0] * wv;
    a1 += rT[k][pg * 4 + 1] * wv;
    a2 += rT[k][pg * 4 + 2] * wv;
    a3 += rT[k][pg * 4 + 3] * wv;
  }
  float bb = b1f[o];
  const float* xp = xin + (size_t)(b * C_ + o) * HW_ + yx0 + pg * 4;
  const float4 xv = *(const float4*)xp;
  float h0 = fmaxf(a0 + bb, 0.f) + xv.x;
  float h1 = fmaxf(a1 + bb, 0.f) + xv.y;
  float h2 = fmaxf(a2 + bb, 0.f) + xv.z;
  float h3 = fmaxf(a3 + bb, 0.f) + xv.w;
  hT[o][pg * 4 + 0] = h0;
  hT[o][pg * 4 + 1] = h1;
  hT[o][pg * 4 + 2] = h2;
  hT[o][pg * 4 + 3] = h3;
  __syncthreads();

  float bo = b2[o];
  float c0 = bo, c1 = bo, c2 = bo, c3 = bo;
#pragma unroll 8
  for (int k = 0; k < 64; ++k) {
    float wv = w2T[k * 64 + o];
    c0 += hT[k][pg * 4 + 0] * wv;
    c1 += hT[k][pg * 4 + 1] * wv;
    c2 += hT[k][pg * 4 + 2] * wv;
    c3 += hT[k][pg * 4 + 3] * wv;
  }
  float* op = out + (size_t)(b * C_ + o) * HW_ + yx0 + pg * 4;
  *(float4*)op = make_float4(c0, c1, c2, c3);
}

extern "C" void kernel_launch(void* const* d_in, const int* in_sizes, int n_in,
                              void* d_out, int out_size, void* d_ws, size_t ws_size,
                              hipStream_t stream) {
  const float* x = (const float*)d_in[0];
  const float* offw = (const float*)d_in[1];
  const float* offb = (const float*)d_in[2];
  const float* dw = (const float*)d_in[3];
  const float* db = (const float*)d_in[4];
  const float* w1 = (const float*)d_in[5];
  const float* b1 = (const float*)d_in[6];
  const float* gamma = (const float*)d_in[7];
  const float* beta = (const float*)d_in[8];
  const float* rmean = (const float*)d_in[9];
  const float* rvar = (const float*)d_in[10];
  const float* w2 = (const float*)d_in[11];
  const float* b2 = (const float*)d_in[12];
  float* out = (float*)d_out;

  float* ws = (float*)d_ws;
  float* p = ws;                        // 8388608 f
  float* off = p + 8388608;             // 2359296 f
  float* rbuf = off + 2359296;          // 8388608 f
  unsigned short* wf = (unsigned short*)(rbuf + 8388608);  // 36864 bf16
  float* w1f = rbuf + 8388608 + 36864;  // 4096 f
  float* w2T = w1f + 4096;              // 4096 f
  float* b1f = w2T + 4096;              // 64 f

  prep_kernel<<<177, 256, 0, stream>>>(dw, w1, b1, gamma, beta, rmean, rvar, w2,
                                       wf, w1f, w2T, b1f);
  avgpool_kernel<<<32768, 256, 0, stream>>>(x, p);
  offconv_kernel<<<512, 256, 0, stream>>>(p, offw, offb, off);
  deform_kernel<<<8192, 256, 0, stream>>>(p, off, wf, db, rbuf);
  tail_kernel<<<8192, 256, 0, stream>>>(rbuf, x, w1f, b1f, w2T, b2, out);
}

// Round 9
// 183.697 us; speedup vs baseline: 5.4605x; 1.5117x over previous
//
#include <hip/hip_runtime.h>
#include <cstddef>

#define H_ 128
#define W_ 128
#define HW_ 16384
#define C_ 64
#define B_ 8
#define BHW_ 131072
#define EPS_ 1e-5f

// A/B shared k-map for deform GEMM: k = kk*68 + c  (c<64 valid, 64..67 zero)
// k-slots s = 0..18 (19*32 = 608 = 9*68 - 4 ... covers all positions)
#define KSLOTS 19
#define ROWS 616  // sAb row stride in shorts (308 dwords)

typedef __attribute__((ext_vector_type(8))) short bf16x8;
typedef __attribute__((ext_vector_type(4))) float f32x4;

__device__ __forceinline__ unsigned short f2bf(float f) {
  unsigned u = __float_as_uint(f);
  unsigned r = (u + 0x7FFFu + ((u >> 16) & 1u)) >> 16;
  return (unsigned short)r;
}

// ---------------- prep: pack all GEMM weights into MFMA fragment order ------
// wf2: deform weights, k-map kk*68+c, 19 slots; w1p/w2p: 1x1 convs, k = c,
// 2 slots, BN folded into w1p; b1f folded bias.
__global__ __launch_bounds__(256) void prep_kernel(
    const float* __restrict__ dw, const float* __restrict__ w1,
    const float* __restrict__ b1, const float* __restrict__ gamma,
    const float* __restrict__ beta, const float* __restrict__ rmean,
    const float* __restrict__ rvar, const float* __restrict__ w2,
    unsigned short* __restrict__ wf2, unsigned short* __restrict__ w1p,
    unsigned short* __restrict__ w2p, float* __restrict__ b1f) {
  int i = blockIdx.x * 256 + threadIdx.x;
  if (i < 38912) {  // 19 sg * 4 og * 64 l * 8 j
    int j = i & 7, l = (i >> 3) & 63, og = (i >> 9) & 3, sg = i >> 11;
    int o = og * 16 + (l & 15);
    int k = sg * 32 + ((l >> 4) << 3) + j;   // 0..607
    int kk = k / 68, c = k - kk * 68;
    float v = (c < 64) ? dw[o * 576 + c * 9 + kk] : 0.f;
    wf2[i] = f2bf(v);
  } else if (i < 38912 + 4096) {
    int j2 = i - 38912;
    int j = j2 & 7, l = (j2 >> 3) & 63, og = (j2 >> 9) & 3, sg = j2 >> 11;
    int o = og * 16 + (l & 15);
    int c = sg * 32 + ((l >> 4) << 3) + j;
    float inv = gamma[o] * rsqrtf(rvar[o] + EPS_);
    w1p[j2] = f2bf(w1[o * 64 + c] * inv);
  } else if (i < 38912 + 8192) {
    int j2 = i - 38912 - 4096;
    int j = j2 & 7, l = (j2 >> 3) & 63, og = (j2 >> 9) & 3, sg = j2 >> 11;
    int o = og * 16 + (l & 15);
    int c = sg * 32 + ((l >> 4) << 3) + j;
    w2p[j2] = f2bf(w2[o * 64 + c]);
  } else if (i < 38912 + 8192 + 64) {
    int o = i - 38912 - 8192;
    float inv = gamma[o] * rsqrtf(rvar[o] + EPS_);
    b1f[o] = b1[o] * inv + beta[o] - rmean[o] * inv;
  }
}

// ---------------- avg pool 3x3, vectorized: 4 px / thread ----------------
__global__ __launch_bounds__(256) void avgpool_kernel(const float* __restrict__ xin,
                                                      float* __restrict__ p) {
  int i = blockIdx.x * 256 + threadIdx.x;  // over BHW*C/4
  int gi = i * 4;
  int bc = gi >> 14;
  int yx = gi & 16383;
  int y = yx >> 7, x0 = yx & 127;
  const float* q = xin + (size_t)bc * HW_;
  float s0 = 0.f, s1 = 0.f, s2 = 0.f, s3 = 0.f;
#pragma unroll
  for (int dy = -1; dy <= 1; ++dy) {
    int yy = y + dy;
    if ((unsigned)yy < 128u) {
      const float* row = q + yy * W_;
      float4 m = *(const float4*)(row + x0);
      float lft = (x0 > 0) ? row[x0 - 1] : 0.f;
      float rgt = (x0 < 124) ? row[x0 + 4] : 0.f;
      s0 += lft + m.x + m.y;
      s1 += m.x + m.y + m.z;
      s2 += m.y + m.z + m.w;
      s3 += m.z + m.w + rgt;
    }
  }
  *(float4*)(p + gi) = make_float4(s0 * (1.f / 9.f), s1 * (1.f / 9.f),
                                   s2 * (1.f / 9.f), s3 * (1.f / 9.f));
}

// ---------------- offset conv: p(64ch) -> off(18ch), 3x3, pad 1 (unchanged) --
__global__ __launch_bounds__(256) void offconv_kernel(
    const float* __restrict__ p, const float* __restrict__ offw,
    const float* __restrict__ offb, float* __restrict__ off) {
  __shared__ float wlds[576 * 20];
  int t = threadIdx.x;
#pragma unroll
  for (int it = 0; it < 45; ++it) {
    int i = it * 256 + t;
    int kidx = i / 20;
    int oc = i - kidx * 20;
    int c = kidx & 63, kk = kidx >> 6;
    wlds[i] = (oc < 18) ? offw[oc * 576 + c * 9 + kk] : 0.f;
  }
  __syncthreads();

  int pix = blockIdx.x * 256 + t;
  int b = pix >> 14;
  int yx = pix & 16383;
  int y = yx >> 7, x = yx & 127;
  const float* pb = p + (size_t)b * C_ * HW_;

  int off9[9];
  float vm9[9];
#pragma unroll
  for (int kk = 0; kk < 9; ++kk) {
    int yy = y + (kk / 3) - 1;
    int xx = x + (kk % 3) - 1;
    bool v = ((unsigned)yy < 128u) && ((unsigned)xx < 128u);
    int yyc = min(max(yy, 0), 127), xxc = min(max(xx, 0), 127);
    off9[kk] = yyc * W_ + xxc;
    vm9[kk] = v ? 1.f : 0.f;
  }

  float acc[20];
#pragma unroll
  for (int j = 0; j < 20; ++j) acc[j] = 0.f;

#pragma unroll
  for (int kk = 0; kk < 9; ++kk) {
    const float* pk = pb + off9[kk];
    float vm = vm9[kk];
    const float* wk = wlds + kk * 64 * 20;
#pragma unroll 4
    for (int c = 0; c < 64; ++c) {
      float v = pk[c * HW_] * vm;
      const float4* w4 = (const float4*)(wk + c * 20);
#pragma unroll
      for (int j = 0; j < 5; ++j) {
        float4 w = w4[j];
        acc[j * 4 + 0] += v * w.x;
        acc[j * 4 + 1] += v * w.y;
        acc[j * 4 + 2] += v * w.z;
        acc[j * 4 + 3] += v * w.w;
      }
    }
  }

  float* op = off + (size_t)(b * 18) * HW_ + yx;
#pragma unroll
  for (int oc = 0; oc < 18; ++oc) op[(size_t)oc * HW_] = acc[oc] + offb[oc];
}

// ---------------- fused deform + conv1/BN/ReLU/residual + conv2 -------------
// Block: 256 thr (4 waves), 16 pixels. Channel-contig p-tile, per-thread
// (pixl,kk) vectorized sampling (b128 corner reads, b64 A-writes), 19-slot
// MFMA deform GEMM (B from prep-packed global, identical k-map), then MFMA
// tail. Slow path preserves exactness for out-of-tile offsets.
__global__ __launch_bounds__(256, 3) void deform_kernel(
    const float* __restrict__ p, const float* __restrict__ off,
    const unsigned short* __restrict__ wf2, const unsigned short* __restrict__ w1p,
    const unsigned short* __restrict__ w2p, const float* __restrict__ db,
    const float* __restrict__ b1f, const float* __restrict__ b2,
    const float* __restrict__ xin, float* __restrict__ out) {
  __shared__ __align__(16) float tileT[100 * 68];          // 27200 B [rc][c]
  __shared__ __align__(16) unsigned short sAb[16 * ROWS];  // 19712 B [pix][k]
  __shared__ __align__(16) unsigned short rTb[16 * 72];    // 2304 B
  __shared__ __align__(16) unsigned short hTb[16 * 72];    // 2304 B
  __shared__ int wOK[4];
  int t = threadIdx.x;
  int lane = t & 63, wv = t >> 6;
  int l15 = lane & 15, lp = lane >> 4;
  int pix0 = blockIdx.x * 16;
  int b = pix0 >> 14;
  int yx0 = pix0 & 16383;
  int y = yx0 >> 7, x0 = yx0 & 127;
  int ty = min(max(y - 2, 0), 123);
  int tx = min(max(x0 - 2, 0), 108);
  const float* pb = p + (size_t)b * C_ * HW_;

  // early residual load (hides under sampling/GEMM)
  int o_me = wv * 16 + l15;
  int px0 = lp * 4;
  const float4 xv = *(const float4*)(xin + (size_t)(b * C_ + o_me) * HW_ + yx0 + px0);

  // ---- bilinear params in registers; thread (pixl = t&15, kk = t>>4) ----
  bool ok = true;
  float w0 = 0.f, w1_ = 0.f, w2_ = 0.f, w3_ = 0.f;
  int rc0 = 0, rc1 = 0, rc2 = 0, rc3 = 0;
  int i0 = 0, i1 = 0, i2 = 0, i3 = 0;
  int pixl = t & 15, kk = t >> 4;
  bool active = (t < 144);
  if (active) {
    int xx = x0 + pixl;
    const float* ob = off + (size_t)(b * 18 + kk * 2) * HW_ + y * W_ + xx;
    float offy = ob[0];
    float offx = ob[HW_];
    float sy = (float)(y + (kk / 3) - 1) + offy;
    float sx = (float)(xx + (kk % 3) - 1) + offx;
    float fy = floorf(sy), fx = floorf(sx);
    float wy = sy - fy, wx = sx - fx;
    int iy = (int)fy, ix = (int)fx;
    float w[4];
    int id[4], rc[4];
#pragma unroll
    for (int j = 0; j < 4; ++j) {
      int dy = j >> 1, dx = j & 1;
      int yc = iy + dy, xc = ix + dx;
      bool v = ((unsigned)yc < 128u) && ((unsigned)xc < 128u);
      int ycc = min(max(yc, 0), 127), xcc = min(max(xc, 0), 127);
      float wgt = (dy ? wy : 1.f - wy) * (dx ? wx : 1.f - wx);
      w[j] = v ? wgt : 0.f;
      id[j] = ycc * W_ + xcc;
      bool in_tile = (ycc >= ty) && (ycc <= ty + 4) && (xcc >= tx) && (xcc <= tx + 19);
      ok = ok && ((w[j] == 0.f) || in_tile);
      int ry = min(max(ycc - ty, 0), 4);
      int rx = min(max(xcc - tx, 0), 19);
      rc[j] = ry * 20 + rx;
    }
    w0 = w[0]; w1_ = w[1]; w2_ = w[2]; w3_ = w[3];
    rc0 = rc[0]; rc1 = rc[1]; rc2 = rc[2]; rc3 = rc[3];
    i0 = id[0]; i1 = id[1]; i2 = id[2]; i3 = id[3];
  }
  {
    unsigned long long m = __ballot(ok);
    if (lane == 0) wOK[wv] = (m == ~0ull) ? 1 : 0;
  }

  // ---- stage p-tile [rc][c] channel-contiguous ----
#pragma unroll
  for (int it = 0; it < 25; ++it) {
    int idx = it * 256 + t;  // 0..6399 = c*100 + rc
    int c = idx / 100;
    int rc = idx - c * 100;
    int r = rc / 20, cx = rc - r * 20;
    tileT[rc * 68 + c] = pb[(size_t)c * HW_ + (ty + r) * W_ + tx + cx];
  }
  // zero own k-pad strip (c = 64..67), disjoint from data writes
  if (active) {
    *(uint2*)(sAb + pixl * ROWS + kk * 68 + 64) = make_uint2(0u, 0u);
  }
  __syncthreads();

  bool fast = wOK[0] && wOK[1] && wOK[2] && wOK[3];

  // ---- sampling: thread owns (pixl,kk), loops channels ----
  if (active) {
    unsigned short* wr = sAb + pixl * ROWS + kk * 68;
    if (fast) {
      const float* t0p = tileT + rc0 * 68;
      const float* t1p = tileT + rc1 * 68;
      const float* t2p = tileT + rc2 * 68;
      const float* t3p = tileT + rc3 * 68;
#pragma unroll
      for (int c0 = 0; c0 < 64; c0 += 4) {
        float4 v0 = *(const float4*)(t0p + c0);
        float4 v1 = *(const float4*)(t1p + c0);
        float4 v2 = *(const float4*)(t2p + c0);
        float4 v3 = *(const float4*)(t3p + c0);
        float a = w0 * v0.x + w1_ * v1.x + w2_ * v2.x + w3_ * v3.x;
        float bq = w0 * v0.y + w1_ * v1.y + w2_ * v2.y + w3_ * v3.y;
        float c = w0 * v0.z + w1_ * v1.z + w2_ * v2.z + w3_ * v3.z;
        float d = w0 * v0.w + w1_ * v1.w + w2_ * v2.w + w3_ * v3.w;
        unsigned r0 = (unsigned)f2bf(a) | ((unsigned)f2bf(bq) << 16);
        unsigned r1 = (unsigned)f2bf(c) | ((unsigned)f2bf(d) << 16);
        *(uint2*)(wr + c0) = make_uint2(r0, r1);
      }
    } else {
#pragma unroll 4
      for (int c = 0; c < 64; ++c) {
        const float* pc = pb + (size_t)c * HW_;
        float v = w0 * pc[i0] + w1_ * pc[i1] + w2_ * pc[i2] + w3_ * pc[i3];
        wr[c] = f2bf(v);
      }
    }
  }
  __syncthreads();

  // ---- deform GEMM: 19 slots, wave wv owns og = wv ----
  f32x4 acc;
  {
    float d = db[o_me];
    acc = (f32x4){d, d, d, d};
  }
  const unsigned short* arow = sAb + l15 * ROWS + (lp << 3);
  const bf16x8* wfp = (const bf16x8*)wf2;
#pragma unroll
  for (int s = 0; s < KSLOTS; ++s) {
    bf16x8 a = *(const bf16x8*)(arow + s * 32);
    bf16x8 bw = wfp[(s * 4 + wv) * 64 + lane];
    acc = __builtin_amdgcn_mfma_f32_16x16x32_bf16(a, bw, acc, 0, 0, 0);
  }

  // ---- r -> bf16 LDS [px][o] (D layout verified: px = lp*4+j, o-col = l15) --
#pragma unroll
  for (int j = 0; j < 4; ++j) {
    rTb[(px0 + j) * 72 + o_me] = f2bf(acc[j]);
  }
  __syncthreads();

  // ---- conv1 + BN(+bias) + ReLU + residual ----
  f32x4 acc1;
  {
    float bb = b1f[o_me];
    acc1 = (f32x4){bb, bb, bb, bb};
  }
  const unsigned short* arow1 = rTb + l15 * 72 + (lp << 3);
  const bf16x8* w1f8 = (const bf16x8*)w1p;
#pragma unroll
  for (int s = 0; s < 2; ++s) {
    bf16x8 a = *(const bf16x8*)(arow1 + s * 32);
    bf16x8 bw = w1f8[(s * 4 + wv) * 64 + lane];
    acc1 = __builtin_amdgcn_mfma_f32_16x16x32_bf16(a, bw, acc1, 0, 0, 0);
  }
  float h0 = fmaxf(acc1[0], 0.f) + xv.x;
  float h1 = fmaxf(acc1[1], 0.f) + xv.y;
  float h2 = fmaxf(acc1[2], 0.f) + xv.z;
  float h3 = fmaxf(acc1[3], 0.f) + xv.w;
  hTb[(px0 + 0) * 72 + o_me] = f2bf(h0);
  hTb[(px0 + 1) * 72 + o_me] = f2bf(h1);
  hTb[(px0 + 2) * 72 + o_me] = f2bf(h2);
  hTb[(px0 + 3) * 72 + o_me] = f2bf(h3);
  __syncthreads();

  // ---- conv2 ----
  f32x4 acc2;
  {
    float bo = b2[o_me];
    acc2 = (f32x4){bo, bo, bo, bo};
  }
  const unsigned short* arow2 = hTb + l15 * 72 + (lp << 3);
  const bf16x8* w2f8 = (const bf16x8*)w2p;
#pragma unroll
  for (int s = 0; s < 2; ++s) {
    bf16x8 a = *(const bf16x8*)(arow2 + s * 32);
    bf16x8 bw = w2f8[(s * 4 + wv) * 64 + lane];
    acc2 = __builtin_amdgcn_mfma_f32_16x16x32_bf16(a, bw, acc2, 0, 0, 0);
  }
  *(float4*)(out + (size_t)(b * C_ + o_me) * HW_ + yx0 + px0) =
      make_float4(acc2[0], acc2[1], acc2[2], acc2[3]);
}

extern "C" void kernel_launch(void* const* d_in, const int* in_sizes, int n_in,
                              void* d_out, int out_size, void* d_ws, size_t ws_size,
                              hipStream_t stream) {
  const float* x = (const float*)d_in[0];
  const float* offw = (const float*)d_in[1];
  const float* offb = (const float*)d_in[2];
  const float* dw = (const float*)d_in[3];
  const float* db = (const float*)d_in[4];
  const float* w1 = (const float*)d_in[5];
  const float* b1 = (const float*)d_in[6];
  const float* gamma = (const float*)d_in[7];
  const float* beta = (const float*)d_in[8];
  const float* rmean = (const float*)d_in[9];
  const float* rvar = (const float*)d_in[10];
  const float* w2 = (const float*)d_in[11];
  const float* b2 = (const float*)d_in[12];
  float* out = (float*)d_out;

  float* ws = (float*)d_ws;
  float* p = ws;                       // 8388608 f
  float* off = p + 8388608;            // 2359296 f
  unsigned short* wf2 = (unsigned short*)(off + 2359296);  // 38912 bf16
  unsigned short* w1p = wf2 + 38912;   // 4096 bf16
  unsigned short* w2p = w1p + 4096;    // 4096 bf16
  float* b1f = (float*)(w2p + 4096);   // 64 f

  prep_kernel<<<185, 256, 0, stream>>>(dw, w1, b1, gamma, beta, rmean, rvar, w2,
                                       wf2, w1p, w2p, b1f);
  avgpool_kernel<<<8192, 256, 0, stream>>>(x, p);
  offconv_kernel<<<512, 256, 0, stream>>>(p, offw, offb, off);
  deform_kernel<<<8192, 256, 0, stream>>>(p, off, wf2, w1p, w2p, db, b1f, b2, x, out);
}